// Round 1
// baseline (473.304 us; speedup 1.0000x reference)
//
#include <hip/hip_runtime.h>
#include <math.h>

// Problem constants
#define NQc 40000
#define Dc 256
#define NHc 8
#define DHc 32
#define NPc 4
#define Wc 200
#define Hc 200

// ---------------------------------------------------------------------------
// Tiled fp32 GEMM building block: BM=64, BN=64, BK=16, 256 threads, 4x4 micro
// ---------------------------------------------------------------------------

// v = query @ W_v + b_v, stored head-major: Vt[h][m][d], n = h*32+d
__global__ __launch_bounds__(256) void gemm_v_kernel(
    const float* __restrict__ A,    // (NQ,256) query
    const float* __restrict__ B,    // (256,256) W_v
    const float* __restrict__ bias, // (256)
    float* __restrict__ Vt)         // (NH, NQ, DH)
{
  __shared__ float As[16][68];  // [k][m], padded to kill write conflicts
  __shared__ float Bs[16][64];  // [k][n]
  const int m0 = blockIdx.x * 64;
  const int n0 = blockIdx.y * 64;
  const int tid = threadIdx.x;
  const int tx = tid & 15, ty = tid >> 4;
  const int lm = tid >> 2;          // A tile row 0..63
  const int lk = (tid & 3) * 4;     // A tile k 0,4,8,12
  const int bk = tid >> 4;          // B tile k 0..15
  const int bn = (tid & 15) * 4;    // B tile n 0..60
  float acc[4][4] = {};
  for (int k0 = 0; k0 < 256; k0 += 16) {
    float4 av = *(const float4*)&A[(size_t)(m0 + lm) * 256 + k0 + lk];
    float4 bv = *(const float4*)&B[(size_t)(k0 + bk) * 256 + n0 + bn];
    __syncthreads();
    As[lk + 0][lm] = av.x; As[lk + 1][lm] = av.y;
    As[lk + 2][lm] = av.z; As[lk + 3][lm] = av.w;
    *(float4*)&Bs[bk][bn] = bv;
    __syncthreads();
#pragma unroll
    for (int kk = 0; kk < 16; ++kk) {
      float a[4], b[4];
      *(float4*)a = *(const float4*)&As[kk][ty * 4];
      *(float4*)b = *(const float4*)&Bs[kk][tx * 4];
#pragma unroll
      for (int i = 0; i < 4; ++i)
#pragma unroll
        for (int j = 0; j < 4; ++j) acc[i][j] = fmaf(a[i], b[j], acc[i][j]);
    }
  }
  const int nb = n0 + tx * 4;
  const int h = nb >> 5, dd = nb & 31;   // 4-span never crosses a head boundary
  float bi[4];
  *(float4*)bi = *(const float4*)&bias[nb];
#pragma unroll
  for (int i = 0; i < 4; ++i) {
    const int m = m0 + ty * 4 + i;
    float4 o;
    o.x = acc[i][0] + bi[0]; o.y = acc[i][1] + bi[1];
    o.z = acc[i][2] + bi[2]; o.w = acc[i][3] + bi[3];
    *(float4*)&Vt[((size_t)h * NQc + m) * DHc + dd] = o;
  }
}

// [so | aw] = qwh @ [W_so | W_aw] + bias, qwh = [query, query+query_pos] (K=512)
// blockIdx.y: 0,1 -> W_so column tiles (N=128); 2 -> W_aw (N=64, softmax over p)
__global__ __launch_bounds__(256) void gemm_soaw_kernel(
    const float* __restrict__ query, const float* __restrict__ query_pos,
    const float* __restrict__ W_so, const float* __restrict__ b_so,
    const float* __restrict__ W_aw, const float* __restrict__ b_aw,
    float* __restrict__ so_ws,   // (NQ,128)
    float* __restrict__ aw_ws)   // (NQ,64) softmaxed
{
  __shared__ float As[16][68];
  __shared__ float Bs[16][64];
  const int m0 = blockIdx.x * 64;
  const int n0 = blockIdx.y * 64;
  const bool is_aw = (n0 >= 128);
  const float* __restrict__ Bp   = is_aw ? W_aw : W_so;
  const float* __restrict__ bp   = is_aw ? b_aw : b_so;
  const int ldb   = is_aw ? 64 : 128;
  const int nbase = is_aw ? 0 : n0;
  const int tid = threadIdx.x;
  const int tx = tid & 15, ty = tid >> 4;
  const int lm = tid >> 2;
  const int lk = (tid & 3) * 4;
  const int bk = tid >> 4;
  const int bn = (tid & 15) * 4;
  float acc[4][4] = {};
  for (int k0 = 0; k0 < 512; k0 += 16) {
    const int kg = k0 + lk;
    float4 av;
    if (kg < 256) {
      av = *(const float4*)&query[(size_t)(m0 + lm) * 256 + kg];
    } else {
      float4 a1 = *(const float4*)&query[(size_t)(m0 + lm) * 256 + kg - 256];
      float4 a2 = *(const float4*)&query_pos[(size_t)(m0 + lm) * 256 + kg - 256];
      av.x = a1.x + a2.x; av.y = a1.y + a2.y; av.z = a1.z + a2.z; av.w = a1.w + a2.w;
    }
    float4 bv = *(const float4*)&Bp[(size_t)(k0 + bk) * ldb + nbase + bn];
    __syncthreads();
    As[lk + 0][lm] = av.x; As[lk + 1][lm] = av.y;
    As[lk + 2][lm] = av.z; As[lk + 3][lm] = av.w;
    *(float4*)&Bs[bk][bn] = bv;
    __syncthreads();
#pragma unroll
    for (int kk = 0; kk < 16; ++kk) {
      float a[4], b[4];
      *(float4*)a = *(const float4*)&As[kk][ty * 4];
      *(float4*)b = *(const float4*)&Bs[kk][tx * 4];
#pragma unroll
      for (int i = 0; i < 4; ++i)
#pragma unroll
        for (int j = 0; j < 4; ++j) acc[i][j] = fmaf(a[i], b[j], acc[i][j]);
    }
  }
  const int nb = nbase + tx * 4;
  float bi[4];
  *(float4*)bi = *(const float4*)&bp[nb];
  if (!is_aw) {
#pragma unroll
    for (int i = 0; i < 4; ++i) {
      const int m = m0 + ty * 4 + i;
      float4 o;
      o.x = acc[i][0] + bi[0]; o.y = acc[i][1] + bi[1];
      o.z = acc[i][2] + bi[2]; o.w = acc[i][3] + bi[3];
      *(float4*)&so_ws[(size_t)m * 128 + nb] = o;
    }
  } else {
    // each thread's 4 columns are exactly one softmax group (h,q fixed, p=0..3)
#pragma unroll
    for (int i = 0; i < 4; ++i) {
      const int m = m0 + ty * 4 + i;
      float v0 = acc[i][0] + bi[0], v1 = acc[i][1] + bi[1];
      float v2 = acc[i][2] + bi[2], v3 = acc[i][3] + bi[3];
      float mx = fmaxf(fmaxf(v0, v1), fmaxf(v2, v3));
      float e0 = expf(v0 - mx), e1 = expf(v1 - mx);
      float e2 = expf(v2 - mx), e3 = expf(v3 - mx);
      float inv = 1.0f / (e0 + e1 + e2 + e3);
      float4 o; o.x = e0 * inv; o.y = e1 * inv; o.z = e2 * inv; o.w = e3 * inv;
      *(float4*)&aw_ws[(size_t)m * 64 + nb] = o;
    }
  }
}

// ---------------------------------------------------------------------------
// Deformable bilinear sampling; averages the two queues.
// block = 1 query, 256 threads = 8 heads x 32 dims.
// ---------------------------------------------------------------------------
__device__ __forceinline__ float sample_corner(const float* __restrict__ vh,
                                               int ix, int iy, float cw, int d) {
  const bool valid = (ix >= 0) & (ix < Wc) & (iy >= 0) & (iy < Hc);
  const int cx = min(max(ix, 0), Wc - 1);
  const int cy = min(max(iy, 0), Hc - 1);
  float g = vh[((size_t)(cy * Wc + cx)) * DHc + d];
  return valid ? g * cw : 0.0f;
}

__global__ __launch_bounds__(256) void sample_kernel(
    const float* __restrict__ vt,     // (NH, NQ, DH)
    const float* __restrict__ so_ws,  // (NQ, 128)
    const float* __restrict__ aw_ws,  // (NQ, 64)
    const float* __restrict__ refp,   // (NQ, 2)
    float* __restrict__ out_pre)      // (NQ, 256)
{
  const int m = blockIdx.x;
  const int tid = threadIdx.x;
  const int h = tid >> 5;
  const int d = tid & 31;
  const float rx = refp[m * 2 + 0] * (float)Wc;
  const float ry = refp[m * 2 + 1] * (float)Hc;
  const float* __restrict__ vh = vt + (size_t)h * NQc * DHc;
  float acc = 0.0f;
#pragma unroll
  for (int q = 0; q < 2; ++q) {
#pragma unroll
    for (int p = 0; p < NPc; ++p) {
      const int c = (h * 2 + q) * 4 + p;
      const float sx = so_ws[(size_t)m * 128 + c * 2 + 0];
      const float sy = so_ws[(size_t)m * 128 + c * 2 + 1];
      const float w  = aw_ws[(size_t)m * 64 + c];
      const float x = rx + sx - 0.5f;
      const float y = ry + sy - 0.5f;
      const float x0f = floorf(x), y0f = floorf(y);
      const int x0 = (int)x0f, y0 = (int)y0f;
      const float wx1 = x - x0f, wx0 = 1.0f - wx1;
      const float wy1 = y - y0f, wy0 = 1.0f - wy1;
      float s = 0.0f;
      s += sample_corner(vh, x0,     y0,     wx0 * wy0, d);
      s += sample_corner(vh, x0 + 1, y0,     wx1 * wy0, d);
      s += sample_corner(vh, x0,     y0 + 1, wx0 * wy1, d);
      s += sample_corner(vh, x0 + 1, y0 + 1, wx1 * wy1, d);
      acc = fmaf(w, s, acc);
    }
  }
  out_pre[(size_t)m * 256 + h * 32 + d] = 0.5f * acc;  // mean over NQUEUE=2
}

// out = out_pre @ W_o + b_o  (plain row-major output)
__global__ __launch_bounds__(256) void gemm_o_kernel(
    const float* __restrict__ A,    // (NQ,256)
    const float* __restrict__ B,    // (256,256)
    const float* __restrict__ bias, // (256)
    float* __restrict__ C)          // (NQ,256)
{
  __shared__ float As[16][68];
  __shared__ float Bs[16][64];
  const int m0 = blockIdx.x * 64;
  const int n0 = blockIdx.y * 64;
  const int tid = threadIdx.x;
  const int tx = tid & 15, ty = tid >> 4;
  const int lm = tid >> 2;
  const int lk = (tid & 3) * 4;
  const int bk = tid >> 4;
  const int bn = (tid & 15) * 4;
  float acc[4][4] = {};
  for (int k0 = 0; k0 < 256; k0 += 16) {
    float4 av = *(const float4*)&A[(size_t)(m0 + lm) * 256 + k0 + lk];
    float4 bv = *(const float4*)&B[(size_t)(k0 + bk) * 256 + n0 + bn];
    __syncthreads();
    As[lk + 0][lm] = av.x; As[lk + 1][lm] = av.y;
    As[lk + 2][lm] = av.z; As[lk + 3][lm] = av.w;
    *(float4*)&Bs[bk][bn] = bv;
    __syncthreads();
#pragma unroll
    for (int kk = 0; kk < 16; ++kk) {
      float a[4], b[4];
      *(float4*)a = *(const float4*)&As[kk][ty * 4];
      *(float4*)b = *(const float4*)&Bs[kk][tx * 4];
#pragma unroll
      for (int i = 0; i < 4; ++i)
#pragma unroll
        for (int j = 0; j < 4; ++j) acc[i][j] = fmaf(a[i], b[j], acc[i][j]);
    }
  }
  const int nb = n0 + tx * 4;
  float bi[4];
  *(float4*)bi = *(const float4*)&bias[nb];
#pragma unroll
  for (int i = 0; i < 4; ++i) {
    const int m = m0 + ty * 4 + i;
    float4 o;
    o.x = acc[i][0] + bi[0]; o.y = acc[i][1] + bi[1];
    o.z = acc[i][2] + bi[2]; o.w = acc[i][3] + bi[3];
    *(float4*)&C[(size_t)m * 256 + nb] = o;
  }
}

extern "C" void kernel_launch(void* const* d_in, const int* in_sizes, int n_in,
                              void* d_out, int out_size, void* d_ws, size_t ws_size,
                              hipStream_t stream) {
  const float* query     = (const float*)d_in[0];
  const float* query_pos = (const float*)d_in[1];
  const float* refp      = (const float*)d_in[2];
  const float* W_so      = (const float*)d_in[3];
  const float* b_so      = (const float*)d_in[4];
  const float* W_aw      = (const float*)d_in[5];
  const float* b_aw      = (const float*)d_in[6];
  const float* W_v       = (const float*)d_in[7];
  const float* b_v       = (const float*)d_in[8];
  const float* W_o       = (const float*)d_in[9];
  const float* b_o       = (const float*)d_in[10];
  float* out = (float*)d_out;

  // workspace layout (fp32 elements): 112.6 MB total
  float* vt      = (float*)d_ws;                         // NH*NQ*DH = 10.24M
  float* so_ws   = vt + (size_t)NHc * NQc * DHc;         // NQ*128   =  5.12M
  float* aw_ws   = so_ws + (size_t)NQc * 128;            // NQ*64    =  2.56M
  float* out_pre = aw_ws + (size_t)NQc * 64;             // NQ*256   = 10.24M

  gemm_v_kernel<<<dim3(NQc / 64, 4), 256, 0, stream>>>(query, W_v, b_v, vt);
  gemm_soaw_kernel<<<dim3(NQc / 64, 3), 256, 0, stream>>>(query, query_pos,
      W_so, b_so, W_aw, b_aw, so_ws, aw_ws);
  sample_kernel<<<dim3(NQc), 256, 0, stream>>>(vt, so_ws, aw_ws, refp, out_pre);
  gemm_o_kernel<<<dim3(NQc / 64, 4), 256, 0, stream>>>(out_pre, W_o, b_o, out);
}

// Round 2
// 408.594 us; speedup vs baseline: 1.1584x; 1.1584x over previous
//
#include <hip/hip_runtime.h>
#include <math.h>

#define NQc 40000
#define Wc 200
#define Hc 200

typedef __attribute__((ext_vector_type(8))) short short8;
typedef __attribute__((ext_vector_type(4))) float f32x4;

__device__ __forceinline__ ushort f2b(float f) {
  unsigned u = __float_as_uint(f);
  u = (u + 0x7fffu + ((u >> 16) & 1u)) >> 16;
  return (ushort)u;
}
__device__ __forceinline__ float b2f(ushort u) {
  return __uint_as_float(((unsigned)u) << 16);
}

// ---------------------------------------------------------------------------
// prep: activations -> bf16 Aq = [query | query+query_pos]  (NQ, 512)
// ---------------------------------------------------------------------------
__global__ __launch_bounds__(256) void prep_act(const float* __restrict__ q,
                                                const float* __restrict__ qp,
                                                ushort* __restrict__ Aq) {
  const int idx = blockIdx.x * 256 + threadIdx.x;  // one float4 of a 256-col row
  const int m = idx >> 6;
  const int c = (idx & 63) * 4;
  float4 a = *(const float4*)&q[(size_t)m * 256 + c];
  float4 b = *(const float4*)&qp[(size_t)m * 256 + c];
  ushort4 o1 = { f2b(a.x), f2b(a.y), f2b(a.z), f2b(a.w) };
  ushort4 o2 = { f2b(a.x + b.x), f2b(a.y + b.y), f2b(a.z + b.z), f2b(a.w + b.w) };
  *(ushort4*)&Aq[(size_t)m * 512 + c] = o1;
  *(ushort4*)&Aq[(size_t)m * 512 + 256 + c] = o2;
}

// weights -> bf16, transposed to (N, K) so B-frag loads are contiguous in k
__global__ __launch_bounds__(256) void prep_w(
    const float* __restrict__ Wv, const float* __restrict__ Wo,
    const float* __restrict__ Wso, const float* __restrict__ Waw,
    ushort* __restrict__ WvT, ushort* __restrict__ WoT,
    ushort* __restrict__ WsoT, ushort* __restrict__ WawT) {
  const int idx = blockIdx.x * 256 + threadIdx.x;
  if (idx < 65536) {                       // WvT (256,256)
    int n = idx >> 8, k = idx & 255;
    WvT[idx] = f2b(Wv[k * 256 + n]);
  } else if (idx < 131072) {               // WoT (256,256)
    int i = idx - 65536;
    int n = i >> 8, k = i & 255;
    WoT[i] = f2b(Wo[k * 256 + n]);
  } else if (idx < 196608) {               // WsoT (128,512)
    int i = idx - 131072;
    int n = i >> 9, k = i & 511;
    WsoT[i] = f2b(Wso[k * 128 + n]);
  } else {                                 // WawT (64,512)
    int i = idx - 196608;
    int n = i >> 9, k = i & 511;
    WawT[i] = f2b(Waw[k * 64 + n]);
  }
}

// ---------------------------------------------------------------------------
// bf16 MFMA GEMM core: block tile 128(M) x 64(N), BK=64, 256 threads (4 waves)
// wave w: rows [w*32, w*32+32), 2x4 grid of 16x16x32 MFMA tiles
// A: (M,K) row-major bf16, lda; BT: (N,K) row-major bf16 (pre-transposed)
// ---------------------------------------------------------------------------
__device__ __forceinline__ void gemm_core(
    const ushort* __restrict__ A, int lda, int K,
    const ushort* __restrict__ BT, int m0, int n0,
    ushort (*As)[72], ushort (*Bs)[72], f32x4* acc) {
  const int tid = threadIdx.x;
  uint4 areg[4], breg[2];

  auto load_tiles = [&](int k0) {
#pragma unroll
    for (int i = 0; i < 4; ++i) {
      const int c = tid + i * 256;
      const int row = c >> 3, kc = (c & 7) * 8;
      const int m = min(m0 + row, NQc - 1);
      areg[i] = *(const uint4*)&A[(size_t)m * lda + k0 + kc];
    }
#pragma unroll
    for (int i = 0; i < 2; ++i) {
      const int c = tid + i * 256;
      const int n = c >> 3, kc = (c & 7) * 8;
      breg[i] = *(const uint4*)&BT[(size_t)(n0 + n) * K + k0 + kc];
    }
  };

  load_tiles(0);
  const int w = tid >> 6, lane = tid & 63;
  const int rl = lane & 15;
  const int kq = (lane >> 4) * 8;

  for (int k0 = 0; k0 < K; k0 += 64) {
    __syncthreads();
#pragma unroll
    for (int i = 0; i < 4; ++i) {
      const int c = tid + i * 256;
      *(uint4*)&As[c >> 3][(c & 7) * 8] = areg[i];
    }
#pragma unroll
    for (int i = 0; i < 2; ++i) {
      const int c = tid + i * 256;
      *(uint4*)&Bs[c >> 3][(c & 7) * 8] = breg[i];
    }
    __syncthreads();
    if (k0 + 64 < K) load_tiles(k0 + 64);
#pragma unroll
    for (int kk = 0; kk < 2; ++kk) {
      short8 af[2], bf[4];
#pragma unroll
      for (int mi = 0; mi < 2; ++mi)
        af[mi] = *(const short8*)&As[w * 32 + mi * 16 + rl][kk * 32 + kq];
#pragma unroll
      for (int nj = 0; nj < 4; ++nj)
        bf[nj] = *(const short8*)&Bs[nj * 16 + rl][kk * 32 + kq];
#pragma unroll
      for (int mi = 0; mi < 2; ++mi)
#pragma unroll
        for (int nj = 0; nj < 4; ++nj)
          acc[mi * 4 + nj] = __builtin_amdgcn_mfma_f32_16x16x32_bf16(
              af[mi], bf[nj], acc[mi * 4 + nj], 0, 0, 0);
    }
  }
}
// Output mapping per acc[mi*4+nj] reg r:
//   m = m0 + w*32 + mi*16 + (lane>>4)*4 + r ; n = n0 + nj*16 + (lane&15)

// v = A1 @ WvT + b_v -> bf16 head-major vt (NH, NQ, 32)
__global__ __launch_bounds__(256) void gemm_v_k(
    const ushort* __restrict__ Aq, const ushort* __restrict__ WvT,
    const float* __restrict__ bv, ushort* __restrict__ vt) {
  __shared__ ushort As[128][72];
  __shared__ ushort Bs[64][72];
  f32x4 acc[8] = {};
  const int m0 = blockIdx.x * 128, n0 = blockIdx.y * 64;
  gemm_core(Aq, 512, 256, WvT, m0, n0, As, Bs, acc);
  const int lane = threadIdx.x & 63, w = threadIdx.x >> 6;
  const int rbase = (lane >> 4) * 4, cl = lane & 15;
#pragma unroll
  for (int mi = 0; mi < 2; ++mi)
#pragma unroll
    for (int nj = 0; nj < 4; ++nj) {
      const int n = n0 + nj * 16 + cl;
      const int h = n >> 5, d = n & 31;
      const float bb = bv[n];
#pragma unroll
      for (int r = 0; r < 4; ++r) {
        const int m = m0 + w * 32 + mi * 16 + rbase + r;
        if (m < NQc) vt[((size_t)h * NQc + m) * 32 + d] = f2b(acc[mi * 4 + nj][r] + bb);
      }
    }
}

// [so|aw] = Aq @ [WsoT|WawT]; y=0,1 -> so (fp32), y=2 -> aw (softmax over p)
__global__ __launch_bounds__(256) void gemm_soaw_k(
    const ushort* __restrict__ Aq,
    const ushort* __restrict__ WsoT, const ushort* __restrict__ WawT,
    const float* __restrict__ b_so, const float* __restrict__ b_aw,
    float* __restrict__ so_ws, float* __restrict__ aw_ws) {
  __shared__ ushort As[128][72];
  __shared__ ushort Bs[64][72];
  f32x4 acc[8] = {};
  const bool is_aw = (blockIdx.y == 2);
  const int m0 = blockIdx.x * 128;
  const int n0 = is_aw ? 0 : blockIdx.y * 64;
  gemm_core(Aq, 512, 512, is_aw ? WawT : WsoT, m0, n0, As, Bs, acc);
  const int lane = threadIdx.x & 63, w = threadIdx.x >> 6;
  const int rbase = (lane >> 4) * 4, cl = lane & 15;
  if (!is_aw) {
#pragma unroll
    for (int mi = 0; mi < 2; ++mi)
#pragma unroll
      for (int nj = 0; nj < 4; ++nj) {
        const int n = n0 + nj * 16 + cl;
        const float bb = b_so[n];
#pragma unroll
        for (int r = 0; r < 4; ++r) {
          const int m = m0 + w * 32 + mi * 16 + rbase + r;
          if (m < NQc) so_ws[(size_t)m * 128 + n] = acc[mi * 4 + nj][r] + bb;
        }
      }
  } else {
    // softmax group = 4 consecutive cols = lanes xor {1,2} (h,queue fixed, p=0..3)
#pragma unroll
    for (int mi = 0; mi < 2; ++mi)
#pragma unroll
      for (int nj = 0; nj < 4; ++nj) {
        const int n = nj * 16 + cl;
        const float bb = b_aw[n];
#pragma unroll
        for (int r = 0; r < 4; ++r) {
          float z = acc[mi * 4 + nj][r] + bb;
          float zm = fmaxf(z, __shfl_xor(z, 1, 64));
          zm = fmaxf(zm, __shfl_xor(zm, 2, 64));
          float e = expf(z - zm);
          float s = e + __shfl_xor(e, 1, 64);
          s = s + __shfl_xor(s, 2, 64);
          const int m = m0 + w * 32 + mi * 16 + rbase + r;
          if (m < NQc) aw_ws[(size_t)m * 64 + n] = e / s;
        }
      }
  }
}

// out = out_pre @ WoT + b_o -> fp32 (NQ,256)
__global__ __launch_bounds__(256) void gemm_o_k(
    const ushort* __restrict__ Ap, const ushort* __restrict__ WoT,
    const float* __restrict__ bo, float* __restrict__ out) {
  __shared__ ushort As[128][72];
  __shared__ ushort Bs[64][72];
  f32x4 acc[8] = {};
  const int m0 = blockIdx.x * 128, n0 = blockIdx.y * 64;
  gemm_core(Ap, 256, 256, WoT, m0, n0, As, Bs, acc);
  const int lane = threadIdx.x & 63, w = threadIdx.x >> 6;
  const int rbase = (lane >> 4) * 4, cl = lane & 15;
#pragma unroll
  for (int mi = 0; mi < 2; ++mi)
#pragma unroll
    for (int nj = 0; nj < 4; ++nj) {
      const int n = n0 + nj * 16 + cl;
      const float bb = bo[n];
#pragma unroll
      for (int r = 0; r < 4; ++r) {
        const int m = m0 + w * 32 + mi * 16 + rbase + r;
        if (m < NQc) out[(size_t)m * 256 + n] = acc[mi * 4 + nj][r] + bb;
      }
    }
}

// ---------------------------------------------------------------------------
// Deformable bilinear sampling (bf16 v), averages two queues.
// block = 1 query, 256 threads = 8 heads x 32 dims
// ---------------------------------------------------------------------------
__device__ __forceinline__ float sample_corner_b(const ushort* __restrict__ vh,
                                                 int ix, int iy, float cw, int d) {
  const bool valid = (ix >= 0) & (ix < Wc) & (iy >= 0) & (iy < Hc);
  const int cx = min(max(ix, 0), Wc - 1);
  const int cy = min(max(iy, 0), Hc - 1);
  float g = b2f(vh[((size_t)(cy * Wc + cx)) * 32 + d]);
  return valid ? g * cw : 0.0f;
}

__global__ __launch_bounds__(256) void sample_kernel(
    const ushort* __restrict__ vt,    // (NH, NQ, 32) bf16
    const float* __restrict__ so_ws,  // (NQ, 128)
    const float* __restrict__ aw_ws,  // (NQ, 64)
    const float* __restrict__ refp,   // (NQ, 2)
    ushort* __restrict__ out_pre)     // (NQ, 256) bf16
{
  const int m = blockIdx.x;
  const int tid = threadIdx.x;
  const int h = tid >> 5;
  const int d = tid & 31;
  const float rx = refp[m * 2 + 0] * (float)Wc;
  const float ry = refp[m * 2 + 1] * (float)Hc;
  const ushort* __restrict__ vh = vt + (size_t)h * NQc * 32;
  float acc = 0.0f;
#pragma unroll
  for (int q = 0; q < 2; ++q) {
#pragma unroll
    for (int p = 0; p < 4; ++p) {
      const int c = (h * 2 + q) * 4 + p;
      const float sx = so_ws[(size_t)m * 128 + c * 2 + 0];
      const float sy = so_ws[(size_t)m * 128 + c * 2 + 1];
      const float wgt = aw_ws[(size_t)m * 64 + c];
      const float x = rx + sx - 0.5f;
      const float y = ry + sy - 0.5f;
      const float x0f = floorf(x), y0f = floorf(y);
      const int x0 = (int)x0f, y0 = (int)y0f;
      const float wx1 = x - x0f, wx0 = 1.0f - wx1;
      const float wy1 = y - y0f, wy0 = 1.0f - wy1;
      float s = 0.0f;
      s += sample_corner_b(vh, x0,     y0,     wx0 * wy0, d);
      s += sample_corner_b(vh, x0 + 1, y0,     wx1 * wy0, d);
      s += sample_corner_b(vh, x0,     y0 + 1, wx0 * wy1, d);
      s += sample_corner_b(vh, x0 + 1, y0 + 1, wx1 * wy1, d);
      acc = fmaf(wgt, s, acc);
    }
  }
  out_pre[(size_t)m * 256 + h * 32 + d] = f2b(0.5f * acc);
}

extern "C" void kernel_launch(void* const* d_in, const int* in_sizes, int n_in,
                              void* d_out, int out_size, void* d_ws, size_t ws_size,
                              hipStream_t stream) {
  const float* query     = (const float*)d_in[0];
  const float* query_pos = (const float*)d_in[1];
  const float* refp      = (const float*)d_in[2];
  const float* W_so      = (const float*)d_in[3];
  const float* b_so      = (const float*)d_in[4];
  const float* W_aw      = (const float*)d_in[5];
  const float* b_aw      = (const float*)d_in[6];
  const float* W_v       = (const float*)d_in[7];
  const float* b_v       = (const float*)d_in[8];
  const float* W_o       = (const float*)d_in[9];
  const float* b_o       = (const float*)d_in[10];
  float* out = (float*)d_out;

  // workspace layout (bytes), total ~92.6 MB (round-1 used 112.6 MB -> fits)
  char* base = (char*)d_ws;
  ushort* Aq      = (ushort*)base;                       // 40,960,000 B (dead after gemm_soaw)
  ushort* out_pre = (ushort*)base;                       // 20,480,000 B (aliases Aq)
  ushort* vt      = (ushort*)(base + 40960000);          // 20,480,000 B
  float*  so_ws   = (float*)(base + 61440000);           // 20,480,000 B
  float*  aw_ws   = (float*)(base + 81920000);           // 10,240,000 B
  ushort* WvT     = (ushort*)(base + 92160000);          // 131,072 B
  ushort* WoT     = WvT + 65536;                         // 131,072 B
  ushort* WsoT    = WoT + 65536;                         // 131,072 B
  ushort* WawT    = WsoT + 65536;                        //  65,536 B

  prep_act<<<40000 * 64 / 256, 256, 0, stream>>>(query, query_pos, Aq);
  prep_w<<<896, 256, 0, stream>>>(W_v, W_o, W_so, W_aw, WvT, WoT, WsoT, WawT);
  gemm_v_k<<<dim3(313, 4), 256, 0, stream>>>(Aq, WvT, b_v, vt);
  gemm_soaw_k<<<dim3(313, 3), 256, 0, stream>>>(Aq, WsoT, WawT, b_so, b_aw, so_ws, aw_ws);
  sample_kernel<<<40000, 256, 0, stream>>>(vt, so_ws, aw_ws, refp, out_pre);
  gemm_o_k<<<dim3(313, 4), 256, 0, stream>>>(out_pre, WoT, b_o, out);
}

// Round 3
// 365.819 us; speedup vs baseline: 1.2938x; 1.1169x over previous
//
#include <hip/hip_runtime.h>
#include <math.h>

#define NQc 40000
#define Wc 200
#define Hc 200

typedef __attribute__((ext_vector_type(8))) short short8;
typedef __attribute__((ext_vector_type(4))) float f32x4;

__device__ __forceinline__ ushort f2b(float f) {
  unsigned u = __float_as_uint(f);
  u = (u + 0x7fffu + ((u >> 16) & 1u)) >> 16;
  return (ushort)u;
}

// ---------------------------------------------------------------------------
// prep: activations -> bf16 Aq = [query | query+query_pos] (NQ,512);
// weights -> bf16 transposed (N,K). One kernel, branch on blockIdx.
// ---------------------------------------------------------------------------
__global__ __launch_bounds__(256) void prep_all(
    const float* __restrict__ q, const float* __restrict__ qp,
    const float* __restrict__ Wv, const float* __restrict__ Wo,
    const float* __restrict__ Wso, const float* __restrict__ Waw,
    ushort* __restrict__ Aq, ushort* __restrict__ WvT, ushort* __restrict__ WoT,
    ushort* __restrict__ WsoT, ushort* __restrict__ WawT) {
  const int b = blockIdx.x;
  if (b < 10000) {
    const int idx = b * 256 + threadIdx.x;  // one float4 of a 256-col row
    const int m = idx >> 6;
    const int c = (idx & 63) * 4;
    float4 a = *(const float4*)&q[(size_t)m * 256 + c];
    float4 p = *(const float4*)&qp[(size_t)m * 256 + c];
    ushort4 o1 = { f2b(a.x), f2b(a.y), f2b(a.z), f2b(a.w) };
    ushort4 o2 = { f2b(a.x + p.x), f2b(a.y + p.y), f2b(a.z + p.z), f2b(a.w + p.w) };
    *(ushort4*)&Aq[(size_t)m * 512 + c] = o1;
    *(ushort4*)&Aq[(size_t)m * 512 + 256 + c] = o2;
  } else {
    const int idx = (b - 10000) * 256 + threadIdx.x;
    if (idx < 65536) {                       // WvT (256,256)
      int n = idx >> 8, k = idx & 255;
      WvT[idx] = f2b(Wv[k * 256 + n]);
    } else if (idx < 131072) {               // WoT (256,256)
      int i = idx - 65536;
      int n = i >> 8, k = i & 255;
      WoT[i] = f2b(Wo[k * 256 + n]);
    } else if (idx < 196608) {               // WsoT (128,512)
      int i = idx - 131072;
      int n = i >> 9, k = i & 511;
      WsoT[i] = f2b(Wso[k * 128 + n]);
    } else {                                 // WawT (64,512)
      int i = idx - 196608;
      int n = i >> 9, k = i & 511;
      WawT[i] = f2b(Waw[k * 64 + n]);
    }
  }
}

// ---------------------------------------------------------------------------
// bf16 MFMA GEMM core: block tile 128(M) x 64(N), BK=64, 256 threads (4 waves)
// ---------------------------------------------------------------------------
__device__ __forceinline__ void gemm_core(
    const ushort* __restrict__ A, int lda, int K,
    const ushort* __restrict__ BT, int m0, int n0,
    ushort (*As)[72], ushort (*Bs)[72], f32x4* acc) {
  const int tid = threadIdx.x;
  uint4 areg[4], breg[2];

  auto load_tiles = [&](int k0) {
#pragma unroll
    for (int i = 0; i < 4; ++i) {
      const int c = tid + i * 256;
      const int row = c >> 3, kc = (c & 7) * 8;
      const int m = min(m0 + row, NQc - 1);
      areg[i] = *(const uint4*)&A[(size_t)m * lda + k0 + kc];
    }
#pragma unroll
    for (int i = 0; i < 2; ++i) {
      const int c = tid + i * 256;
      const int n = c >> 3, kc = (c & 7) * 8;
      breg[i] = *(const uint4*)&BT[(size_t)(n0 + n) * K + k0 + kc];
    }
  };

  load_tiles(0);
  const int w = tid >> 6, lane = tid & 63;
  const int rl = lane & 15;
  const int kq = (lane >> 4) * 8;

  for (int k0 = 0; k0 < K; k0 += 64) {
    __syncthreads();
#pragma unroll
    for (int i = 0; i < 4; ++i) {
      const int c = tid + i * 256;
      *(uint4*)&As[c >> 3][(c & 7) * 8] = areg[i];
    }
#pragma unroll
    for (int i = 0; i < 2; ++i) {
      const int c = tid + i * 256;
      *(uint4*)&Bs[c >> 3][(c & 7) * 8] = breg[i];
    }
    __syncthreads();
    if (k0 + 64 < K) load_tiles(k0 + 64);
#pragma unroll
    for (int kk = 0; kk < 2; ++kk) {
      short8 af[2], bf[4];
#pragma unroll
      for (int mi = 0; mi < 2; ++mi)
        af[mi] = *(const short8*)&As[w * 32 + mi * 16 + rl][kk * 32 + kq];
#pragma unroll
      for (int nj = 0; nj < 4; ++nj)
        bf[nj] = *(const short8*)&Bs[nj * 16 + rl][kk * 32 + kq];
#pragma unroll
      for (int mi = 0; mi < 2; ++mi)
#pragma unroll
        for (int nj = 0; nj < 4; ++nj)
          acc[mi * 4 + nj] = __builtin_amdgcn_mfma_f32_16x16x32_bf16(
              af[mi], bf[nj], acc[mi * 4 + nj], 0, 0, 0);
    }
  }
}
// acc[mi*4+nj] reg r: m = m0+w*32+mi*16+(lane>>4)*4+r ; n = n0+nj*16+(lane&15)

// v = query @ WvT + b_v -> bf16 head-major vt (NH, NQ, 32)
__global__ __launch_bounds__(256) void gemm_v_k(
    const ushort* __restrict__ Aq, const ushort* __restrict__ WvT,
    const float* __restrict__ bv, ushort* __restrict__ vt) {
  __shared__ ushort As[128][72];
  __shared__ ushort Bs[64][72];
  f32x4 acc[8] = {};
  const int m0 = blockIdx.x * 128, n0 = blockIdx.y * 64;
  gemm_core(Aq, 512, 256, WvT, m0, n0, As, Bs, acc);
  const int lane = threadIdx.x & 63, w = threadIdx.x >> 6;
  const int rbase = (lane >> 4) * 4, cl = lane & 15;
#pragma unroll
  for (int mi = 0; mi < 2; ++mi)
#pragma unroll
    for (int nj = 0; nj < 4; ++nj) {
      const int n = n0 + nj * 16 + cl;
      const int h = n >> 5, d = n & 31;
      const float bb = bv[n];
#pragma unroll
      for (int r = 0; r < 4; ++r) {
        const int m = m0 + w * 32 + mi * 16 + rbase + r;
        if (m < NQc) vt[((size_t)h * NQc + m) * 32 + d] = f2b(acc[mi * 4 + nj][r] + bb);
      }
    }
}

// [so|aw] = Aq @ [WsoT|WawT]; y=0,1 -> so (fp32), y=2 -> aw (softmax over p)
__global__ __launch_bounds__(256) void gemm_soaw_k(
    const ushort* __restrict__ Aq,
    const ushort* __restrict__ WsoT, const ushort* __restrict__ WawT,
    const float* __restrict__ b_so, const float* __restrict__ b_aw,
    float* __restrict__ so_ws, float* __restrict__ aw_ws) {
  __shared__ ushort As[128][72];
  __shared__ ushort Bs[64][72];
  f32x4 acc[8] = {};
  const bool is_aw = (blockIdx.y == 2);
  const int m0 = blockIdx.x * 128;
  const int n0 = is_aw ? 0 : blockIdx.y * 64;
  gemm_core(Aq, 512, 512, is_aw ? WawT : WsoT, m0, n0, As, Bs, acc);
  const int lane = threadIdx.x & 63, w = threadIdx.x >> 6;
  const int rbase = (lane >> 4) * 4, cl = lane & 15;
  if (!is_aw) {
#pragma unroll
    for (int mi = 0; mi < 2; ++mi)
#pragma unroll
      for (int nj = 0; nj < 4; ++nj) {
        const int n = n0 + nj * 16 + cl;
        const float bb = b_so[n];
#pragma unroll
        for (int r = 0; r < 4; ++r) {
          const int m = m0 + w * 32 + mi * 16 + rbase + r;
          if (m < NQc) so_ws[(size_t)m * 128 + n] = acc[mi * 4 + nj][r] + bb;
        }
      }
  } else {
    // softmax group = 4 consecutive cols = lanes xor {1,2}
#pragma unroll
    for (int mi = 0; mi < 2; ++mi)
#pragma unroll
      for (int nj = 0; nj < 4; ++nj) {
        const int n = nj * 16 + cl;
        const float bb = b_aw[n];
#pragma unroll
        for (int r = 0; r < 4; ++r) {
          float z = acc[mi * 4 + nj][r] + bb;
          float zm = fmaxf(z, __shfl_xor(z, 1, 64));
          zm = fmaxf(zm, __shfl_xor(zm, 2, 64));
          float e = expf(z - zm);
          float s = e + __shfl_xor(e, 1, 64);
          s = s + __shfl_xor(s, 2, 64);
          const int m = m0 + w * 32 + mi * 16 + rbase + r;
          if (m < NQc) aw_ws[(size_t)m * 64 + n] = e / s;
        }
      }
  }
}

// out = out_pre @ WoT + b_o -> fp32 (NQ,256)
__global__ __launch_bounds__(256) void gemm_o_k(
    const ushort* __restrict__ Ap, const ushort* __restrict__ WoT,
    const float* __restrict__ bo, float* __restrict__ out) {
  __shared__ ushort As[128][72];
  __shared__ ushort Bs[64][72];
  f32x4 acc[8] = {};
  const int m0 = blockIdx.x * 128, n0 = blockIdx.y * 64;
  gemm_core(Ap, 256, 256, WoT, m0, n0, As, Bs, acc);
  const int lane = threadIdx.x & 63, w = threadIdx.x >> 6;
  const int rbase = (lane >> 4) * 4, cl = lane & 15;
#pragma unroll
  for (int mi = 0; mi < 2; ++mi)
#pragma unroll
    for (int nj = 0; nj < 4; ++nj) {
      const int n = n0 + nj * 16 + cl;
      const float bb = bo[n];
#pragma unroll
      for (int r = 0; r < 4; ++r) {
        const int m = m0 + w * 32 + mi * 16 + rbase + r;
        if (m < NQc) out[(size_t)m * 256 + n] = acc[mi * 4 + nj][r] + bb;
      }
    }
}

// ---------------------------------------------------------------------------
// Deformable sampling, restructured:
//   block = ONE head x 32 queries; head = blockIdx.x & 7 -> pins each head's
//   2.56 MB vt slice to one XCD's L2 (round-robin block->XCD dispatch).
//   Phase 1: 256 threads compute 256 corner descriptors (offsets+weights) ->LDS
//   Phase 2: lane handles 4 d-values, ushort4 (8B) loads per corner.
// ---------------------------------------------------------------------------
__global__ __launch_bounds__(256) void sample_kernel(
    const ushort* __restrict__ vt,    // (NH, NQ, 32) bf16
    const float* __restrict__ so_ws,  // (NQ, 128)
    const float* __restrict__ aw_ws,  // (NQ, 64)
    const float* __restrict__ refp,   // (NQ, 2)
    ushort* __restrict__ out_pre)     // (NQ, 256) bf16
{
  __shared__ int   offs[8][32][4];    // [j=q*4+p][qi][corner] element offsets
  __shared__ float wts [8][32][4];
  const int h  = blockIdx.x & 7;
  const int m0 = (blockIdx.x >> 3) * 32;
  const int tid = threadIdx.x;

  // ---- phase 1: descriptors (one per thread) ----
  {
    const int j  = tid & 7;          // q*4 + p
    const int qi = tid >> 3;
    const int m  = m0 + qi;
    const int c  = h * 8 + j;
    const float sx  = so_ws[(size_t)m * 128 + c * 2 + 0];
    const float sy  = so_ws[(size_t)m * 128 + c * 2 + 1];
    const float wgt = aw_ws[(size_t)m * 64 + c];
    const float x = refp[m * 2 + 0] * (float)Wc + sx - 0.5f;
    const float y = refp[m * 2 + 1] * (float)Hc + sy - 0.5f;
    const float x0f = floorf(x), y0f = floorf(y);
    const int x0 = (int)x0f, y0 = (int)y0f;
    const int x1 = x0 + 1, y1 = y0 + 1;
    const float wx1 = x - x0f, wx0 = 1.0f - wx1;
    const float wy1 = y - y0f, wy0 = 1.0f - wy1;
    const bool vx0 = (x0 >= 0) & (x0 < Wc), vx1 = (x1 >= 0) & (x1 < Wc);
    const bool vy0 = (y0 >= 0) & (y0 < Hc), vy1 = (y1 >= 0) & (y1 < Hc);
    const int cx0 = min(max(x0, 0), Wc - 1), cx1 = min(max(x1, 0), Wc - 1);
    const int cy0 = min(max(y0, 0), Hc - 1), cy1 = min(max(y1, 0), Hc - 1);
    offs[j][qi][0] = (cy0 * Wc + cx0) * 32;
    offs[j][qi][1] = (cy0 * Wc + cx1) * 32;
    offs[j][qi][2] = (cy1 * Wc + cx0) * 32;
    offs[j][qi][3] = (cy1 * Wc + cx1) * 32;
    wts[j][qi][0] = (vx0 & vy0) ? wgt * wx0 * wy0 : 0.0f;
    wts[j][qi][1] = (vx1 & vy0) ? wgt * wx1 * wy0 : 0.0f;
    wts[j][qi][2] = (vx0 & vy1) ? wgt * wx0 * wy1 : 0.0f;
    wts[j][qi][3] = (vx1 & vy1) ? wgt * wx1 * wy1 : 0.0f;
  }
  __syncthreads();

  // ---- phase 2: gather; lane covers d = ld*4 .. ld*4+3 ----
  const int qi = tid >> 3;
  const int ld = tid & 7;
  const int m  = m0 + qi;
  const ushort* __restrict__ vh = vt + (size_t)h * NQc * 32 + ld * 4;
  float a0 = 0.f, a1 = 0.f, a2 = 0.f, a3 = 0.f;
#pragma unroll
  for (int j = 0; j < 8; ++j) {
    const int4   o = *(const int4*)&offs[j][qi][0];
    const float4 w = *(const float4*)&wts[j][qi][0];
#pragma unroll
    for (int k = 0; k < 4; ++k) {
      const int oo = (k == 0) ? o.x : (k == 1) ? o.y : (k == 2) ? o.z : o.w;
      const float ww = (k == 0) ? w.x : (k == 1) ? w.y : (k == 2) ? w.z : w.w;
      const uint2 raw = *(const uint2*)&vh[oo];
      const float f0 = __uint_as_float(raw.x << 16);
      const float f1 = __uint_as_float(raw.x & 0xFFFF0000u);
      const float f2 = __uint_as_float(raw.y << 16);
      const float f3 = __uint_as_float(raw.y & 0xFFFF0000u);
      a0 = fmaf(ww, f0, a0);
      a1 = fmaf(ww, f1, a1);
      a2 = fmaf(ww, f2, a2);
      a3 = fmaf(ww, f3, a3);
    }
  }
  ushort4 o = { f2b(0.5f * a0), f2b(0.5f * a1), f2b(0.5f * a2), f2b(0.5f * a3) };
  *(ushort4*)&out_pre[(size_t)m * 256 + h * 32 + ld * 4] = o;
}

extern "C" void kernel_launch(void* const* d_in, const int* in_sizes, int n_in,
                              void* d_out, int out_size, void* d_ws, size_t ws_size,
                              hipStream_t stream) {
  const float* query     = (const float*)d_in[0];
  const float* query_pos = (const float*)d_in[1];
  const float* refp      = (const float*)d_in[2];
  const float* W_so      = (const float*)d_in[3];
  const float* b_so      = (const float*)d_in[4];
  const float* W_aw      = (const float*)d_in[5];
  const float* b_aw      = (const float*)d_in[6];
  const float* W_v       = (const float*)d_in[7];
  const float* b_v       = (const float*)d_in[8];
  const float* W_o       = (const float*)d_in[9];
  const float* b_o       = (const float*)d_in[10];
  float* out = (float*)d_out;

  // workspace layout (bytes), total ~92.6 MB
  char* base = (char*)d_ws;
  ushort* Aq      = (ushort*)base;                       // 40,960,000 B (dead after gemm_soaw)
  ushort* out_pre = (ushort*)base;                       // 20,480,000 B (aliases Aq)
  ushort* vt      = (ushort*)(base + 40960000);          // 20,480,000 B
  float*  so_ws   = (float*)(base + 61440000);           // 20,480,000 B
  float*  aw_ws   = (float*)(base + 81920000);           // 10,240,000 B
  ushort* WvT     = (ushort*)(base + 92160000);          // 131,072 B
  ushort* WoT     = WvT + 65536;                         // 131,072 B
  ushort* WsoT    = WoT + 65536;                         // 131,072 B
  ushort* WawT    = WsoT + 65536;                        //  65,536 B

  prep_all<<<10896, 256, 0, stream>>>(query, query_pos, W_v, W_o, W_so, W_aw,
                                      Aq, WvT, WoT, WsoT, WawT);
  gemm_v_k<<<dim3(313, 4), 256, 0, stream>>>(Aq, WvT, b_v, vt);
  gemm_soaw_k<<<dim3(313, 3), 256, 0, stream>>>(Aq, WsoT, WawT, b_so, b_aw, so_ws, aw_ws);
  sample_kernel<<<10000, 256, 0, stream>>>(vt, so_ws, aw_ws, refp, out_pre);
  gemm_o_k<<<dim3(313, 4), 256, 0, stream>>>(out_pre, WoT, b_o, out);
}

// Round 4
// 327.839 us; speedup vs baseline: 1.4437x; 1.1158x over previous
//
#include <hip/hip_runtime.h>
#include <math.h>

#define NQc 40000
#define Wc 200
#define Hc 200

typedef __attribute__((ext_vector_type(8))) short short8;
typedef __attribute__((ext_vector_type(4))) float f32x4;

__device__ __forceinline__ ushort f2b(float f) {
  unsigned u = __float_as_uint(f);
  u = (u + 0x7fffu + ((u >> 16) & 1u)) >> 16;
  return (ushort)u;
}

// ---------------------------------------------------------------------------
// prep: activations -> bf16 Aq = [query | query+query_pos] (NQ,512);
// weights -> bf16 transposed (N,K).
// ---------------------------------------------------------------------------
__global__ __launch_bounds__(256) void prep_all(
    const float* __restrict__ q, const float* __restrict__ qp,
    const float* __restrict__ Wv, const float* __restrict__ Wo,
    const float* __restrict__ Wso, const float* __restrict__ Waw,
    ushort* __restrict__ Aq, ushort* __restrict__ WvT, ushort* __restrict__ WoT,
    ushort* __restrict__ WsoT, ushort* __restrict__ WawT) {
  const int b = blockIdx.x;
  if (b < 10000) {
    const int idx = b * 256 + threadIdx.x;
    const int m = idx >> 6;
    const int c = (idx & 63) * 4;
    float4 a = *(const float4*)&q[(size_t)m * 256 + c];
    float4 p = *(const float4*)&qp[(size_t)m * 256 + c];
    ushort4 o1 = { f2b(a.x), f2b(a.y), f2b(a.z), f2b(a.w) };
    ushort4 o2 = { f2b(a.x + p.x), f2b(a.y + p.y), f2b(a.z + p.z), f2b(a.w + p.w) };
    *(ushort4*)&Aq[(size_t)m * 512 + c] = o1;
    *(ushort4*)&Aq[(size_t)m * 512 + 256 + c] = o2;
  } else {
    const int idx = (b - 10000) * 256 + threadIdx.x;
    if (idx < 65536) {
      int n = idx >> 8, k = idx & 255;
      WvT[idx] = f2b(Wv[k * 256 + n]);
    } else if (idx < 131072) {
      int i = idx - 65536;
      int n = i >> 8, k = i & 255;
      WoT[i] = f2b(Wo[k * 256 + n]);
    } else if (idx < 196608) {
      int i = idx - 131072;
      int n = i >> 9, k = i & 511;
      WsoT[i] = f2b(Wso[k * 128 + n]);
    } else {
      int i = idx - 196608;
      int n = i >> 9, k = i & 511;
      WawT[i] = f2b(Waw[k * 64 + n]);
    }
  }
}

// ---------------------------------------------------------------------------
// bf16 MFMA GEMM core: block tile 128(M) x BN(N), BK=64, 256 threads (4 waves)
// wave w: rows [w*32, w*32+32), 2 x (BN/16) grid of 16x16x32 MFMA tiles
// acc[mi*(BN/16)+nj] reg r: m=m0+w*32+mi*16+(lane>>4)*4+r ; n=nj*16+(lane&15)
// ---------------------------------------------------------------------------
template <int BN>
__device__ __forceinline__ void gemm_core(
    const ushort* __restrict__ A, int lda, int K,
    const ushort* __restrict__ BT, int m0, int n0,
    ushort (*As)[72], ushort (*Bs)[72], f32x4* acc) {
  constexpr int NJ = BN / 16;
  constexpr int NBL = BN / 32;
  const int tid = threadIdx.x;
  uint4 areg[4], breg[NBL];

  auto load_tiles = [&](int k0) {
#pragma unroll
    for (int i = 0; i < 4; ++i) {
      const int c = tid + i * 256;
      const int row = c >> 3, kc = (c & 7) * 8;
      const int m = min(m0 + row, NQc - 1);
      areg[i] = *(const uint4*)&A[(size_t)m * lda + k0 + kc];
    }
#pragma unroll
    for (int i = 0; i < NBL; ++i) {
      const int c = tid + i * 256;
      const int n = c >> 3, kc = (c & 7) * 8;
      breg[i] = *(const uint4*)&BT[(size_t)(n0 + n) * K + k0 + kc];
    }
  };

  load_tiles(0);
  const int w = tid >> 6, lane = tid & 63;
  const int rl = lane & 15;
  const int kq = (lane >> 4) * 8;

  for (int k0 = 0; k0 < K; k0 += 64) {
    __syncthreads();
#pragma unroll
    for (int i = 0; i < 4; ++i) {
      const int c = tid + i * 256;
      *(uint4*)&As[c >> 3][(c & 7) * 8] = areg[i];
    }
#pragma unroll
    for (int i = 0; i < NBL; ++i) {
      const int c = tid + i * 256;
      *(uint4*)&Bs[c >> 3][(c & 7) * 8] = breg[i];
    }
    __syncthreads();
    if (k0 + 64 < K) load_tiles(k0 + 64);
#pragma unroll
    for (int kk = 0; kk < 2; ++kk) {
      short8 af[2], bf[NJ];
#pragma unroll
      for (int mi = 0; mi < 2; ++mi)
        af[mi] = *(const short8*)&As[w * 32 + mi * 16 + rl][kk * 32 + kq];
#pragma unroll
      for (int nj = 0; nj < NJ; ++nj)
        bf[nj] = *(const short8*)&Bs[nj * 16 + rl][kk * 32 + kq];
#pragma unroll
      for (int mi = 0; mi < 2; ++mi)
#pragma unroll
        for (int nj = 0; nj < NJ; ++nj)
          acc[mi * NJ + nj] = __builtin_amdgcn_mfma_f32_16x16x32_bf16(
              af[mi], bf[nj], acc[mi * NJ + nj], 0, 0, 0);
    }
  }
  __syncthreads();  // LDS free for epilogue reuse
}

// v = query @ WvT + b_v -> bf16 head-major vt (NH, NQ, 32).  N=128 (4 heads)
__global__ __launch_bounds__(256, 2) void gemm_v_k(
    const ushort* __restrict__ Aq, const ushort* __restrict__ WvT,
    const float* __restrict__ bv, ushort* __restrict__ vt) {
  __shared__ __align__(16) char smem[36864];
  ushort (*As)[72] = (ushort(*)[72])smem;
  ushort (*Bs)[72] = (ushort(*)[72])(smem + 18432);
  ushort (*Eb)[72] = (ushort(*)[72])smem;   // epilogue staging, aliases As/Bs
  f32x4 acc[16] = {};
  const int m0 = blockIdx.x * 128, n0 = blockIdx.y * 128;
  gemm_core<128>(Aq, 512, 256, WvT, m0, n0, As, Bs, acc);
  const int tid = threadIdx.x;
  const int lane = tid & 63, w = tid >> 6;
  const int rbase = (lane >> 4) * 4, cl = lane & 15;
#pragma unroll
  for (int p = 0; p < 2; ++p) {  // 64-col halves
#pragma unroll
    for (int mi = 0; mi < 2; ++mi)
#pragma unroll
      for (int j = 0; j < 4; ++j) {
        const int n = n0 + p * 64 + j * 16 + cl;
        const float bb = bv[n];
        const f32x4 a = acc[mi * 8 + p * 4 + j];
#pragma unroll
        for (int r = 0; r < 4; ++r)
          Eb[w * 32 + mi * 16 + rbase + r][j * 16 + cl] = f2b(a[r] + bb);
      }
    __syncthreads();
#pragma unroll
    for (int hh = 0; hh < 2; ++hh) {
      const int h = (n0 + p * 64) / 32 + hh;
#pragma unroll
      for (int it = 0; it < 4; ++it) {
        const int flat = it * 256 + tid;
        const int row = flat >> 3, d4 = (flat & 7) * 4;
        if (m0 + row < NQc)
          *(ushort4*)&vt[((size_t)h * NQc + m0 + row) * 32 + d4] =
              *(const ushort4*)&Eb[row][hh * 32 + d4];
      }
    }
    __syncthreads();
  }
}

// [so|aw] = Aq @ [WsoT(128) | WawT(64)] single pass, N=192. so fp32, aw softmaxed
__global__ __launch_bounds__(256, 2) void gemm_soaw_k(
    const ushort* __restrict__ Aq,
    const ushort* __restrict__ WsoT, const ushort* __restrict__ WawT,
    const float* __restrict__ b_so, const float* __restrict__ b_aw,
    float* __restrict__ so_ws, float* __restrict__ aw_ws) {
  __shared__ __align__(16) char smem[46080];
  ushort (*As)[72] = (ushort(*)[72])smem;
  ushort (*Bs)[72] = (ushort(*)[72])(smem + 18432);
  float (*E)[68] = (float(*)[68])smem;
  f32x4 acc[24] = {};
  const int m0 = blockIdx.x * 128;
  const int tid = threadIdx.x;
  // K-loop with split B source: Bs rows 0..127 from WsoT, 128..191 from WawT
  {
    const int K = 512;
    uint4 areg[4], breg[6];
    auto load_tiles = [&](int k0) {
#pragma unroll
      for (int i = 0; i < 4; ++i) {
        const int c = tid + i * 256;
        const int row = c >> 3, kc = (c & 7) * 8;
        const int m = min(m0 + row, NQc - 1);
        areg[i] = *(const uint4*)&Aq[(size_t)m * 512 + k0 + kc];
      }
#pragma unroll
      for (int i = 0; i < 6; ++i) {
        const int c = tid + i * 256;
        const int n = c >> 3, kc = (c & 7) * 8;
        const ushort* src = (n < 128) ? &WsoT[(size_t)n * K + k0 + kc]
                                      : &WawT[(size_t)(n - 128) * K + k0 + kc];
        breg[i] = *(const uint4*)src;
      }
    };
    load_tiles(0);
    const int w = tid >> 6, lane = tid & 63;
    const int rl = lane & 15;
    const int kq = (lane >> 4) * 8;
    for (int k0 = 0; k0 < K; k0 += 64) {
      __syncthreads();
#pragma unroll
      for (int i = 0; i < 4; ++i) {
        const int c = tid + i * 256;
        *(uint4*)&As[c >> 3][(c & 7) * 8] = areg[i];
      }
#pragma unroll
      for (int i = 0; i < 6; ++i) {
        const int c = tid + i * 256;
        *(uint4*)&Bs[c >> 3][(c & 7) * 8] = breg[i];
      }
      __syncthreads();
      if (k0 + 64 < K) load_tiles(k0 + 64);
#pragma unroll
      for (int kk = 0; kk < 2; ++kk) {
        short8 af[2], bf[12];
#pragma unroll
        for (int mi = 0; mi < 2; ++mi)
          af[mi] = *(const short8*)&As[w * 32 + mi * 16 + rl][kk * 32 + kq];
#pragma unroll
        for (int nj = 0; nj < 12; ++nj)
          bf[nj] = *(const short8*)&Bs[nj * 16 + rl][kk * 32 + kq];
#pragma unroll
        for (int mi = 0; mi < 2; ++mi)
#pragma unroll
          for (int nj = 0; nj < 12; ++nj)
            acc[mi * 12 + nj] = __builtin_amdgcn_mfma_f32_16x16x32_bf16(
                af[mi], bf[nj], acc[mi * 12 + nj], 0, 0, 0);
      }
    }
    __syncthreads();
  }
  const int lane = tid & 63, w = tid >> 6;
  const int rbase = (lane >> 4) * 4, cl = lane & 15;
  // passes 0,1: so cols 0-63 / 64-127 ; pass 2: aw (softmax over 4-col groups)
#pragma unroll
  for (int p = 0; p < 3; ++p) {
#pragma unroll
    for (int mi = 0; mi < 2; ++mi)
#pragma unroll
      for (int j = 0; j < 4; ++j) {
        const int nj = p * 4 + j;
        const int nl = j * 16 + cl;  // 0..63 within pass
        const f32x4 a = acc[mi * 12 + nj];
        if (p < 2) {
          const float bb = b_so[p * 64 + nl];
#pragma unroll
          for (int r = 0; r < 4; ++r)
            E[w * 32 + mi * 16 + rbase + r][nl] = a[r] + bb;
        } else {
          const float bb = b_aw[nl];
#pragma unroll
          for (int r = 0; r < 4; ++r) {
            float z = a[r] + bb;
            float zm = fmaxf(z, __shfl_xor(z, 1, 64));
            zm = fmaxf(zm, __shfl_xor(zm, 2, 64));
            float e = expf(z - zm);
            float s = e + __shfl_xor(e, 1, 64);
            s = s + __shfl_xor(s, 2, 64);
            E[w * 32 + mi * 16 + rbase + r][nl] = e / s;
          }
        }
      }
    __syncthreads();
#pragma unroll
    for (int it = 0; it < 8; ++it) {
      const int flat = it * 256 + tid;
      const int row = flat >> 4, c4 = (flat & 15) * 4;
      if (m0 + row < NQc) {
        const float4 vle = *(const float4*)&E[row][c4];
        if (p < 2)
          *(float4*)&so_ws[(size_t)(m0 + row) * 128 + p * 64 + c4] = vle;
        else
          *(float4*)&aw_ws[(size_t)(m0 + row) * 64 + c4] = vle;
      }
    }
    __syncthreads();
  }
}

// out = out_pre @ WoT + b_o -> fp32 (NQ,256).  N=128 per block
__global__ __launch_bounds__(256, 2) void gemm_o_k(
    const ushort* __restrict__ Ap, const ushort* __restrict__ WoT,
    const float* __restrict__ bo, float* __restrict__ out) {
  __shared__ __align__(16) char smem[36864];
  ushort (*As)[72] = (ushort(*)[72])smem;
  ushort (*Bs)[72] = (ushort(*)[72])(smem + 18432);
  float (*E)[68] = (float(*)[68])smem;
  f32x4 acc[16] = {};
  const int m0 = blockIdx.x * 128, n0 = blockIdx.y * 128;
  gemm_core<128>(Ap, 256, 256, WoT, m0, n0, As, Bs, acc);
  const int tid = threadIdx.x;
  const int lane = tid & 63, w = tid >> 6;
  const int rbase = (lane >> 4) * 4, cl = lane & 15;
#pragma unroll
  for (int p = 0; p < 2; ++p) {
#pragma unroll
    for (int mi = 0; mi < 2; ++mi)
#pragma unroll
      for (int j = 0; j < 4; ++j) {
        const int n = n0 + p * 64 + j * 16 + cl;
        const float bb = bo[n];
        const f32x4 a = acc[mi * 8 + p * 4 + j];
#pragma unroll
        for (int r = 0; r < 4; ++r)
          E[w * 32 + mi * 16 + rbase + r][j * 16 + cl] = a[r] + bb;
      }
    __syncthreads();
#pragma unroll
    for (int it = 0; it < 8; ++it) {
      const int flat = it * 256 + tid;
      const int row = flat >> 4, c4 = (flat & 15) * 4;
      if (m0 + row < NQc)
        *(float4*)&out[(size_t)(m0 + row) * 256 + n0 + p * 64 + c4] =
            *(const float4*)&E[row][c4];
    }
    __syncthreads();
  }
}

// ---------------------------------------------------------------------------
// Deformable sampling: block = one head x 32 queries; head = blockIdx.x & 7
// pins each head's 2.56 MB vt slice to one XCD's L2.
// ---------------------------------------------------------------------------
__global__ __launch_bounds__(256) void sample_kernel(
    const ushort* __restrict__ vt,    // (NH, NQ, 32) bf16
    const float* __restrict__ so_ws,  // (NQ, 128)
    const float* __restrict__ aw_ws,  // (NQ, 64)
    const float* __restrict__ refp,   // (NQ, 2)
    ushort* __restrict__ out_pre)     // (NQ, 256) bf16
{
  __shared__ int   offs[8][32][4];
  __shared__ float wts [8][32][4];
  const int h  = blockIdx.x & 7;
  const int m0 = (blockIdx.x >> 3) * 32;
  const int tid = threadIdx.x;

  {
    const int j  = tid & 7;          // q*4 + p
    const int qi = tid >> 3;
    const int m  = m0 + qi;
    const int c  = h * 8 + j;
    const float sx  = so_ws[(size_t)m * 128 + c * 2 + 0];
    const float sy  = so_ws[(size_t)m * 128 + c * 2 + 1];
    const float wgt = aw_ws[(size_t)m * 64 + c];
    const float x = refp[m * 2 + 0] * (float)Wc + sx - 0.5f;
    const float y = refp[m * 2 + 1] * (float)Hc + sy - 0.5f;
    const float x0f = floorf(x), y0f = floorf(y);
    const int x0 = (int)x0f, y0 = (int)y0f;
    const int x1 = x0 + 1, y1 = y0 + 1;
    const float wx1 = x - x0f, wx0 = 1.0f - wx1;
    const float wy1 = y - y0f, wy0 = 1.0f - wy1;
    const bool vx0 = (x0 >= 0) & (x0 < Wc), vx1 = (x1 >= 0) & (x1 < Wc);
    const bool vy0 = (y0 >= 0) & (y0 < Hc), vy1 = (y1 >= 0) & (y1 < Hc);
    const int cx0 = min(max(x0, 0), Wc - 1), cx1 = min(max(x1, 0), Wc - 1);
    const int cy0 = min(max(y0, 0), Hc - 1), cy1 = min(max(y1, 0), Hc - 1);
    offs[j][qi][0] = (cy0 * Wc + cx0) * 32;
    offs[j][qi][1] = (cy0 * Wc + cx1) * 32;
    offs[j][qi][2] = (cy1 * Wc + cx0) * 32;
    offs[j][qi][3] = (cy1 * Wc + cx1) * 32;
    wts[j][qi][0] = (vx0 & vy0) ? wgt * wx0 * wy0 : 0.0f;
    wts[j][qi][1] = (vx1 & vy0) ? wgt * wx1 * wy0 : 0.0f;
    wts[j][qi][2] = (vx0 & vy1) ? wgt * wx0 * wy1 : 0.0f;
    wts[j][qi][3] = (vx1 & vy1) ? wgt * wx1 * wy1 : 0.0f;
  }
  __syncthreads();

  const int qi = tid >> 3;
  const int ld = tid & 7;
  const int m  = m0 + qi;
  const ushort* __restrict__ vh = vt + (size_t)h * NQc * 32 + ld * 4;
  float a0 = 0.f, a1 = 0.f, a2 = 0.f, a3 = 0.f;
#pragma unroll
  for (int j = 0; j < 8; ++j) {
    const int4   o = *(const int4*)&offs[j][qi][0];
    const float4 w = *(const float4*)&wts[j][qi][0];
#pragma unroll
    for (int k = 0; k < 4; ++k) {
      const int oo = (k == 0) ? o.x : (k == 1) ? o.y : (k == 2) ? o.z : o.w;
      const float ww = (k == 0) ? w.x : (k == 1) ? w.y : (k == 2) ? w.z : w.w;
      const uint2 raw = *(const uint2*)&vh[oo];
      const float f0 = __uint_as_float(raw.x << 16);
      const float f1 = __uint_as_float(raw.x & 0xFFFF0000u);
      const float f2 = __uint_as_float(raw.y << 16);
      const float f3 = __uint_as_float(raw.y & 0xFFFF0000u);
      a0 = fmaf(ww, f0, a0);
      a1 = fmaf(ww, f1, a1);
      a2 = fmaf(ww, f2, a2);
      a3 = fmaf(ww, f3, a3);
    }
  }
  ushort4 o = { f2b(0.5f * a0), f2b(0.5f * a1), f2b(0.5f * a2), f2b(0.5f * a3) };
  *(ushort4*)&out_pre[(size_t)m * 256 + h * 32 + ld * 4] = o;
}

extern "C" void kernel_launch(void* const* d_in, const int* in_sizes, int n_in,
                              void* d_out, int out_size, void* d_ws, size_t ws_size,
                              hipStream_t stream) {
  const float* query     = (const float*)d_in[0];
  const float* query_pos = (const float*)d_in[1];
  const float* refp      = (const float*)d_in[2];
  const float* W_so      = (const float*)d_in[3];
  const float* b_so      = (const float*)d_in[4];
  const float* W_aw      = (const float*)d_in[5];
  const float* b_aw      = (const float*)d_in[6];
  const float* W_v       = (const float*)d_in[7];
  const float* b_v       = (const float*)d_in[8];
  const float* W_o       = (const float*)d_in[9];
  const float* b_o       = (const float*)d_in[10];
  float* out = (float*)d_out;

  // workspace layout (bytes), total ~92.6 MB
  char* base = (char*)d_ws;
  ushort* Aq      = (ushort*)base;                       // 40,960,000 B
  ushort* out_pre = (ushort*)base;                       // aliases Aq (dead)
  ushort* vt      = (ushort*)(base + 40960000);          // 20,480,000 B
  float*  so_ws   = (float*)(base + 61440000);           // 20,480,000 B
  float*  aw_ws   = (float*)(base + 81920000);           // 10,240,000 B
  ushort* WvT     = (ushort*)(base + 92160000);
  ushort* WoT     = WvT + 65536;
  ushort* WsoT    = WoT + 65536;
  ushort* WawT    = WsoT + 65536;

  prep_all<<<10896, 256, 0, stream>>>(query, query_pos, W_v, W_o, W_so, W_aw,
                                      Aq, WvT, WoT, WsoT, WawT);
  gemm_v_k<<<dim3(313, 2), 256, 0, stream>>>(Aq, WvT, b_v, vt);
  gemm_soaw_k<<<313, 256, 0, stream>>>(Aq, WsoT, WawT, b_so, b_aw, so_ws, aw_ws);
  sample_kernel<<<10000, 256, 0, stream>>>(vt, so_ws, aw_ws, refp, out_pre);
  gemm_o_k<<<dim3(313, 2), 256, 0, stream>>>(out_pre, WoT, b_o, out);
}